// Round 9
// baseline (595.081 us; speedup 1.0000x reference)
//
#include <hip/hip_runtime.h>
#include <hip/hip_bf16.h>

// N=65536 points, H=256, 4 hidden layers, ReLU MLP -> (psi,p).
// ReLU => piecewise linear => Hessians vanish; f = p_x, g = p_y (RHO=1).
// Pipeline:
//   1) fp32 forward replicating np/BLAS arithmetic BIT-EXACTLY.
//      v27: 64-point blocks (hT 65.8KB) -> 2 blocks/CU. Theory: the ~68%
//      VALU-duty ceiling (v11..v23: chunking no-op, LDS-broadcast spill,
//      VMEM latency, within-block stagger null) is CORRELATED SMEM drains
//      -- within a block, layer barriers re-sync every wave, so 1 block/CU
//      (140KB hT) means the whole CU idles at each drain. Two
//      barrier-independent blocks/CU give decorrelated phases:
//      duty ~ 1-(1-0.68)^2 ~ 0.90. Per-element arithmetic UNCHANGED
//      (same k-ascending fmaf chains, same operands, same sum order)
//      -> BIT-IDENTICAL masks and p. launch_bounds(1024,8) pins VGPR<=64
//      (body holds 16 accs now; spill watch = FETCH explosion).
//      Risk: 2 divergent-phase weight streams ~2x SMEM pull (~44 B/cyc/CU
//      vs ~57 L2 ceiling) -- if K$ thrashes, gain shrinks (null read:
//      fwd closed for good).
//   2) tangent kernel v26 (UNMODIFIED, ~106us): whole-layer B in registers
//      from FRAGMENT-MAJOR Wt2 (each B-fragment load = 64 lanes x 16B = 1KB
//      contiguous); no Bpan. absmax 6.103516e-05 (f16 tangent path only).
// Workspace: masks 5x2MB | Wt2 512KB

#define NPTS 65536
#define HDIM 256

typedef _Float16 half8_t __attribute__((ext_vector_type(8)));
typedef _Float16 half4_t __attribute__((ext_vector_type(4)));
typedef float floatx4 __attribute__((ext_vector_type(4)));

// ---------------------------------------------------------------- fused fp32 forward (np/BLAS-exact) — v27: 64-pt blocks
__global__ void __launch_bounds__(1024, 8) fwd_fused_kernel(
    const float* __restrict__ x, const float* __restrict__ y, const float* __restrict__ t,
    const float* __restrict__ Win, const float* __restrict__ b_in,
    const float* __restrict__ Wh, const float* __restrict__ b_h,
    const float* __restrict__ Wout, const float* __restrict__ b_out,
    unsigned char* __restrict__ masks, float* __restrict__ out) {
  constexpr int SH = 257;              // odd stride: conflict-free b32
  __shared__ float hT[64 * SH];        // [pt][k]  65792 B
  __shared__ float pscr[16][66];       // wave partials for p (4224 B)

  const int tid = threadIdx.x;
  const int lane = tid & 63;
  const int w = __builtin_amdgcn_readfirstlane(tid >> 6);       // wave id 0..15
  const int c0 = w * 16;                                        // 16-col group
  const int p0 = blockIdx.x * 64;
  const int pA = p0 + lane;            // one point per lane

  // ---- layer 1: dot = z @ Win (k ascending: x,y,t), then + b_in  [bit-exact]
  {
    float xa = x[pA], ya = y[pA], ta = t[pA];
    unsigned ma = 0;
#pragma unroll
    for (int e = 0; e < 16; ++e) {
      int c = c0 + e;                  // uniform -> Win reads are scalar
      float w0 = Win[c], w1 = Win[256 + c], w2 = Win[512 + c], bb = b_in[c];
      float da = fmaf(xa, w0, 0.f);
      da = fmaf(ya, w1, da);
      da = fmaf(ta, w2, da);
      float aa = da + bb;
      bool posa = aa > 0.f;
      hT[lane * SH + c] = posa ? aa : 0.f;
      ma |= (posa ? 1u : 0u) << e;
    }
    *(unsigned short*)(masks + (size_t)pA * 32 + w * 2) = (unsigned short)ma;
  }
  __syncthreads();

  // ---- hidden layers: single fp32 accumulator per element, k ascending, fmaf
  for (int l = 0; l < 4; ++l) {
    const float* Wl = Wh + (size_t)l * 65536 + c0;   // + uniform col offset
    float accA[16] = {};
#pragma unroll 2
    for (int k = 0; k < 256; ++k) {
      float hA = hT[lane * SH + k];          // per-lane LDS, conflict-free
      const float* wr = Wl + k * 256;        // wave-uniform -> s_load_dwordx16
#pragma unroll
      for (int e = 0; e < 16; ++e) {
        float wv = wr[e];
        accA[e] = fmaf(hA, wv, accA[e]);     // k-ascending: bit-exact
      }
    }
    __syncthreads();                   // all hT reads done before overwrite
    unsigned ma = 0;
    float hnA[16];
#pragma unroll
    for (int e = 0; e < 16; ++e) {
      float bb = b_h[l * 256 + c0 + e];
      float aa = accA[e] + bb;
      bool posa = aa > 0.f;
      hnA[e] = posa ? aa : 0.f;
      ma |= (posa ? 1u : 0u) << e;
    }
    *(unsigned short*)(masks + ((size_t)(l + 1) * NPTS + pA) * 32 + w * 2) =
        (unsigned short)ma;
#pragma unroll
    for (int e = 0; e < 16; ++e)
      hT[lane * SH + c0 + e] = hnA[e];
    __syncthreads();
  }

  // ---- p = h5 . Wout[:,1] + b_out[1]
  {
    float sA = 0.f;
#pragma unroll
    for (int e = 0; e < 16; ++e) {
      float wv = Wout[2 * (c0 + e) + 1];
      sA = fmaf(hT[lane * SH + c0 + e], wv, sA);
    }
    pscr[w][lane] = sA;
  }
  __syncthreads();
  if (tid < 64) {
    float s2 = 0.f;
#pragma unroll
    for (int g = 0; g < 16; ++g) s2 += pscr[g][tid];  // same g-order: bit-exact
    out[2 * NPTS + p0 + tid] = s2 + b_out[1];
  }
}

// ---------------------------------------------------------------- prep: Wh fp32 [l][k][n] -> fragment-major f16
// Wt2 flat index i = ((((l*4 + wn)*8 + s)*4 + nj)*64 + lane)*8 + j
// holds (f16)Wh[l][k][n] with k = s*32 + (lane>>4)*8 + j,
//                           n = wn*64 + nj*16 + (lane&15).
// A wave's B-fragment load (fixed l,wn,s,nj; lane 0..63; j 0..7) is then
// 64 x 16B = 1KB contiguous -> one fully-coalesced global_load_dwordx4.
__global__ void __launch_bounds__(256) prep_weights_kernel(
    const float* __restrict__ Wh, _Float16* __restrict__ Wt2) {
  int i = blockIdx.x * 256 + threadIdx.x;   // 0..262143
  int j = i & 7;
  int lane = (i >> 3) & 63;
  int nj = (i >> 9) & 3;
  int s = (i >> 11) & 7;
  int wn = (i >> 14) & 3;
  int l = i >> 16;
  int k = s * 32 + ((lane >> 4) << 3) + j;
  int n = wn * 64 + nj * 16 + (lane & 15);
  Wt2[i] = (_Float16)Wh[(size_t)l * 65536 + (size_t)k * 256 + n];
}

// ---------------------------------------------------------------- fused tangent chain (init + 4 layers + finalize)
// Block: 256 thr = 4 waves. 32 points -> 64 rows (0..31 x-tangent, 32..63 y).
// Tile M=64 x N=256; wave wn owns 64 rows x 64 cols. T lives in Apan (f16).
// v26: whole-layer B in registers (breg[8][4]), loaded from FRAGMENT-MAJOR
// Wt2 -> 32 fully-coalesced 1KB dwordx4 loads per wave per layer at layer
// top (compiler early-issues, counted vmcnt; latency hides under af+MFMA).
// No Bpan. LDS = Apan + smask = 38.9KB.
// mfma(bf, af, acc) OPERAND SWAP -> D[row = n-local quad*4+reg]
// [col = m-local l15]: lane holds 4 consecutive n for one row m ->
// write-back is 16 ds_write_b64. Finalize = one MFMA chain per wave.
// mfma_f32_16x16x32_f16: A[m=lane&15][k=quad*8+j], B[k=quad*8+j][n=lane&15],
//                        D[row=quad*4+reg][col=lane&15]  (verified layouts)
__global__ void __launch_bounds__(256, 2) tangent_fused_kernel(
    const float* __restrict__ Win,
    const _Float16* __restrict__ Wt2,         // fragment-major (see prep)
    const unsigned int* __restrict__ maskDw,  // [5][NPTS][8] dwords
    const float* __restrict__ Wout, float* __restrict__ out) {
  constexpr int SA = 264;   // A row stride (halves): 256 + 8 pad
  __shared__ alignas(16) _Float16 Apan[64 * SA];        // 33792 B
  __shared__ unsigned int smask[5 * 256];               // 5120 B

  const int tid = threadIdx.x;
  const int lane = tid & 63;
  const int wn = tid >> 6;          // wave = 64-col group
  const int l15 = lane & 15, quad = lane >> 4;
  const int p0 = blockIdx.x * 32;   // 32 points per block

  // ---- stage all 5 mask layers (32 pts x 8 dw each)
#pragma unroll
  for (int i = 0; i < 5; ++i)
    smask[i * 256 + tid] = maskDw[(size_t)i * NPTS * 8 + (size_t)p0 * 8 + tid];
  __syncthreads();

  // ---- init T1 into Apan: row<32 -> x-tangent (Win row 0), row>=32 -> y (row 1)
#pragma unroll
  for (int i = 0; i < 8; ++i) {
    int g = tid + 256 * i;          // 0..2047 col-groups of 8
    int row = g >> 5, cg = g & 31;
    int c0 = cg * 8, pt = row & 31, tg = row >> 5;
    unsigned dw = smask[pt * 8 + (c0 >> 5)];
    half8_t v;
#pragma unroll
    for (int e = 0; e < 8; ++e) {
      bool m = (dw >> ((cg & 3) * 8 + e)) & 1;
      v[e] = m ? (_Float16)Win[tg * 256 + c0 + e] : (_Float16)0.f;
    }
    *(half8_t*)&Apan[row * SA + c0] = v;
  }
  __syncthreads();                  // Apan init visible to all waves

  // ---- 4 layers: acc = A @ W_l (computed transposed), gate, back into Apan
  for (int l = 0; l < 4; ++l) {
    // fragment-major base for this (l, wn): fragments are 1KB apart,
    // this wave's lane slice is lane*16B within each.
    const _Float16* Bw = Wt2 + ((size_t)(l * 4 + wn) * 32 + 0) * 512 + (size_t)lane * 8;

    // ---- load ALL 32 B fragments for this layer: fully-coalesced 1KB each.
    half8_t breg[8][4];
#pragma unroll
    for (int s = 0; s < 8; ++s)
#pragma unroll
      for (int nj = 0; nj < 4; ++nj)
        breg[s][nj] = *(const half8_t*)(Bw + (size_t)(s * 4 + nj) * 512);

    floatx4 acc[4][4] = {};   // [mi][nj], element = D[n-local][m-local]
#pragma unroll
    for (int s = 0; s < 8; ++s) {     // s = kp*2+ks of v19: same k order
      half8_t af[4];
#pragma unroll
      for (int mi = 0; mi < 4; ++mi)
        af[mi] = *(const half8_t*)&Apan[(mi * 16 + l15) * SA + s * 32 + quad * 8];
      // SWAPPED operands: same products/order as v19 (bit-identical values),
      // transposed D layout (lane = one T-row m, 4 consecutive n per reg)
#pragma unroll
      for (int mi = 0; mi < 4; ++mi)
#pragma unroll
        for (int nj = 0; nj < 4; ++nj)
          acc[mi][nj] = __builtin_amdgcn_mfma_f32_16x16x32_f16(breg[s][nj], af[mi], acc[mi][nj], 0, 0, 0);
    }
    __syncthreads();          // all Apan reads of this layer done
    // gated write-back: lane (l15,quad) of tile (mi,nj) holds rows m=mi*16+l15,
    // cols C = wn*64 + nj*16 + quad*4 + r  -> one b64 per (mi,nj)
    const unsigned int* ml = &smask[(l + 1) * 256];
    uint2 mA = *(const uint2*)&ml[l15 * 8 + wn * 2];         // pt = l15
    uint2 mB = *(const uint2*)&ml[(16 + l15) * 8 + wn * 2];  // pt = 16+l15
#pragma unroll
    for (int mi = 0; mi < 4; ++mi) {
      uint2 md = (mi & 1) ? mB : mA;
      int m = mi * 16 + l15;
#pragma unroll
      for (int nj = 0; nj < 4; ++nj) {
        unsigned dw = (nj < 2) ? md.x : md.y;
        int bitbase = (nj & 1) * 16 + quad * 4;
        half4_t v;
#pragma unroll
        for (int r = 0; r < 4; ++r)
          v[r] = ((dw >> (bitbase + r)) & 1) ? (_Float16)acc[mi][nj][r]
                                             : (_Float16)0.f;
        *(half4_t*)&Apan[m * SA + wn * 64 + nj * 16 + quad * 4] = v;
      }
    }
    __syncthreads();
  }

  // ---- finalize: T5 @ Wout via one MFMA chain per wave (rows wn*16..+15)
  {
    floatx4 facc = {0.f, 0.f, 0.f, 0.f};
#pragma unroll
    for (int kc = 0; kc < 8; ++kc) {
      half8_t a = *(const half8_t*)&Apan[(wn * 16 + l15) * SA + kc * 32 + quad * 8];
      half8_t b;
#pragma unroll
      for (int j = 0; j < 8; ++j) {
        int k = kc * 32 + quad * 8 + j;
        b[j] = (l15 < 2) ? (_Float16)Wout[2 * k + l15] : (_Float16)0.f;
      }
      facc = __builtin_amdgcn_mfma_f32_16x16x32_f16(a, b, facc, 0, 0, 0);
    }
    // D[row=quad*4+r][col=l15]: global row = wn*16 + quad*4 + r; col 0 -> psi
    // derivative dot (u/v), col 1 -> p derivative dot (f/g)
    if (l15 < 2) {
#pragma unroll
      for (int r = 0; r < 4; ++r) {
        int row = wn * 16 + quad * 4 + r;
        int pt = p0 + (row & 31);
        float val = facc[r];
        if (l15 == 0) {
          if (row < 32) out[NPTS + pt] = -val;      // v = -psi_x
          else          out[pt] = val;              // u =  psi_y
        } else {
          if (row < 32) out[3 * NPTS + pt] = val;   // f = p_x
          else          out[4 * NPTS + pt] = val;   // g = p_y
        }
      }
    }
  }
}

// ---------------------------------------------------------------- launch
extern "C" void kernel_launch(void* const* d_in, const int* in_sizes, int n_in,
                              void* d_out, int out_size, void* d_ws, size_t ws_size,
                              hipStream_t stream) {
  const float* x = (const float*)d_in[0];
  const float* y = (const float*)d_in[1];
  const float* t = (const float*)d_in[2];
  const float* Win = (const float*)d_in[3];
  const float* b_in = (const float*)d_in[4];
  const float* Wh = (const float*)d_in[5];
  const float* b_h = (const float*)d_in[6];
  const float* Wout = (const float*)d_in[7];
  const float* b_out = (const float*)d_in[8];
  float* out = (float*)d_out;

  char* ws = (char*)d_ws;
  constexpr size_t MASK_SZ = (size_t)NPTS * 32;       // 2 MB per layer
  unsigned char* masks = (unsigned char*)ws;
  _Float16* Wt2 = (_Float16*)(ws + 5 * MASK_SZ);

  // weight transpose/cast/swizzle first (independent of fwd)
  prep_weights_kernel<<<1024, 256, 0, stream>>>(Wh, Wt2);

  // fp32 np-exact forward: masks L0..L4 + p  (64 pts/block, 2 blocks/CU)
  fwd_fused_kernel<<<NPTS / 64, 1024, 0, stream>>>(
      x, y, t, Win, b_in, Wh, b_h, Wout, b_out, masks, out);

  // fused tangent chain: init + 4 MFMA layers + finalize (u,v,f,g)
  tangent_fused_kernel<<<NPTS / 32, 256, 0, stream>>>(
      Win, Wt2, (const unsigned int*)masks, Wout, out);
}

// Round 10
// 520.939 us; speedup vs baseline: 1.1423x; 1.1423x over previous
//
#include <hip/hip_runtime.h>
#include <hip/hip_bf16.h>

// N=65536 points, H=256, 4 hidden layers, ReLU MLP -> (psi,p).
// ReLU => piecewise linear => Hessians vanish; f = p_x, g = p_y (RHO=1).
// Pipeline:
//   1) fp32 forward (v20/v11 verbatim, ~400us) - FINAL. Seven experiments
//      (chunk-4, LDS-broadcast, VMEM-broadcast, stagger, 64-pt blocks)
//      bracket the s_load path's ~68% duty as the structural optimum:
//      v27 (1pt/lane, 2 blk/CU) halved intensity per drain + doubled
//      weight traffic -> 504us/54%. Bit-exact np/BLAS chains throughout.
//   2) tangent kernel v28 = v26 + 64 POINTS PER BLOCK (128 tangent rows).
//      v26 (32pt) = 106us vs 33us MFMA floor; dominant cost = B re-fetch
//      (1 GB L2 grid-wide) + only 32 MFMA per 32-fragment batch. 64pt:
//      B traffic halves (512MB), MFMA per B-slice doubles (64 = ~310cyc
//      -> covers L2 latency with depth-1 ping-pong prefetch bb[2][4]).
//      acc[8][4]=128 VGPR + bb 32 + af 32 ~ 215 < 256 cap. LDS 76KB ->
//      2 blocks/CU. Same fragments, same s-order, same mask gating,
//      same finalize chains -> BIT-IDENTICAL output (absmax 6.103516e-05).
// Workspace: masks 5x2MB | Wt2 512KB

#define NPTS 65536
#define HDIM 256

typedef _Float16 half8_t __attribute__((ext_vector_type(8)));
typedef _Float16 half4_t __attribute__((ext_vector_type(4)));
typedef float floatx4 __attribute__((ext_vector_type(4)));

// ---------------------------------------------------------------- fused fp32 forward (np/BLAS-exact) — v11/v20 verbatim
__global__ void __launch_bounds__(1024) fwd_fused_kernel(
    const float* __restrict__ x, const float* __restrict__ y, const float* __restrict__ t,
    const float* __restrict__ Win, const float* __restrict__ b_in,
    const float* __restrict__ Wh, const float* __restrict__ b_h,
    const float* __restrict__ Wout, const float* __restrict__ b_out,
    unsigned char* __restrict__ masks, float* __restrict__ out) {
  constexpr int SH = 257;              // odd stride: conflict-free b32
  __shared__ float hT[128 * SH];       // [pt][k]  131584 B
  __shared__ float pscr[16][132];      // wave partials for p (8448 B)

  const int tid = threadIdx.x;
  const int lane = tid & 63;
  const int w = __builtin_amdgcn_readfirstlane(tid >> 6);       // wave id 0..15
  const int c0 = w * 16;                                        // 16-col group
  const int p0 = blockIdx.x * 128;
  const int pA = p0 + lane;            // point A
  const int pB = p0 + 64 + lane;       // point B

  // ---- layer 1: dot = z @ Win (k ascending: x,y,t), then + b_in  [bit-exact]
  {
    float xa = x[pA], ya = y[pA], ta = t[pA];
    float xb = x[pB], yb = y[pB], tb = t[pB];
    unsigned ma = 0, mb = 0;
#pragma unroll
    for (int e = 0; e < 16; ++e) {
      int c = c0 + e;                  // uniform -> Win reads are scalar
      float w0 = Win[c], w1 = Win[256 + c], w2 = Win[512 + c], bb = b_in[c];
      float da = fmaf(xa, w0, 0.f);
      da = fmaf(ya, w1, da);
      da = fmaf(ta, w2, da);
      float aa = da + bb;
      bool posa = aa > 0.f;
      hT[lane * SH + c] = posa ? aa : 0.f;
      ma |= (posa ? 1u : 0u) << e;
      float db = fmaf(xb, w0, 0.f);
      db = fmaf(yb, w1, db);
      db = fmaf(tb, w2, db);
      float ab = db + bb;
      bool posb = ab > 0.f;
      hT[(64 + lane) * SH + c] = posb ? ab : 0.f;
      mb |= (posb ? 1u : 0u) << e;
    }
    *(unsigned short*)(masks + (size_t)pA * 32 + w * 2) = (unsigned short)ma;
    *(unsigned short*)(masks + (size_t)pB * 32 + w * 2) = (unsigned short)mb;
  }
  __syncthreads();

  // ---- hidden layers: single fp32 accumulator per element, k ascending, fmaf
  for (int l = 0; l < 4; ++l) {
    const float* Wl = Wh + (size_t)l * 65536 + c0;   // + uniform col offset
    float accA[16] = {};
    float accB[16] = {};
#pragma unroll 2
    for (int k = 0; k < 256; ++k) {
      float hA = hT[lane * SH + k];          // per-lane LDS, conflict-free
      float hB = hT[(64 + lane) * SH + k];
      const float* wr = Wl + k * 256;        // wave-uniform -> s_load_dwordx16
#pragma unroll
      for (int e = 0; e < 16; ++e) {
        float wv = wr[e];
        accA[e] = fmaf(hA, wv, accA[e]);
        accB[e] = fmaf(hB, wv, accB[e]);
      }
    }
    __syncthreads();                   // all hT reads done before overwrite
    unsigned ma = 0, mb = 0;
    float hnA[16], hnB[16];
#pragma unroll
    for (int e = 0; e < 16; ++e) {
      float bb = b_h[l * 256 + c0 + e];
      float aa = accA[e] + bb;
      bool posa = aa > 0.f;
      hnA[e] = posa ? aa : 0.f;
      ma |= (posa ? 1u : 0u) << e;
      float ab = accB[e] + bb;
      bool posb = ab > 0.f;
      hnB[e] = posb ? ab : 0.f;
      mb |= (posb ? 1u : 0u) << e;
    }
    *(unsigned short*)(masks + ((size_t)(l + 1) * NPTS + pA) * 32 + w * 2) =
        (unsigned short)ma;
    *(unsigned short*)(masks + ((size_t)(l + 1) * NPTS + pB) * 32 + w * 2) =
        (unsigned short)mb;
#pragma unroll
    for (int e = 0; e < 16; ++e) {
      hT[lane * SH + c0 + e] = hnA[e];
      hT[(64 + lane) * SH + c0 + e] = hnB[e];
    }
    __syncthreads();
  }

  // ---- p = h5 . Wout[:,1] + b_out[1]
  {
    float sA = 0.f, sB = 0.f;
#pragma unroll
    for (int e = 0; e < 16; ++e) {
      float wv = Wout[2 * (c0 + e) + 1];
      sA = fmaf(hT[lane * SH + c0 + e], wv, sA);
      sB = fmaf(hT[(64 + lane) * SH + c0 + e], wv, sB);
    }
    pscr[w][lane] = sA;
    pscr[w][64 + lane] = sB;
  }
  __syncthreads();
  if (tid < 128) {
    float s2 = 0.f;
#pragma unroll
    for (int g = 0; g < 16; ++g) s2 += pscr[g][tid];
    out[2 * NPTS + p0 + tid] = s2 + b_out[1];
  }
}

// ---------------------------------------------------------------- prep: Wh fp32 [l][k][n] -> fragment-major f16
// Wt2 flat index i = ((((l*4 + wn)*8 + s)*4 + nj)*64 + lane)*8 + j
// holds (f16)Wh[l][k][n] with k = s*32 + (lane>>4)*8 + j,
//                           n = wn*64 + nj*16 + (lane&15).
// A wave's B-fragment load (fixed l,wn,s,nj; lane 0..63; j 0..7) is then
// 64 x 16B = 1KB contiguous -> one fully-coalesced global_load_dwordx4.
__global__ void __launch_bounds__(256) prep_weights_kernel(
    const float* __restrict__ Wh, _Float16* __restrict__ Wt2) {
  int i = blockIdx.x * 256 + threadIdx.x;   // 0..262143
  int j = i & 7;
  int lane = (i >> 3) & 63;
  int nj = (i >> 9) & 3;
  int s = (i >> 11) & 7;
  int wn = (i >> 14) & 3;
  int l = i >> 16;
  int k = s * 32 + ((lane >> 4) << 3) + j;
  int n = wn * 64 + nj * 16 + (lane & 15);
  Wt2[i] = (_Float16)Wh[(size_t)l * 65536 + (size_t)k * 256 + n];
}

// ---------------------------------------------------------------- fused tangent chain (init + 4 layers + finalize)
// v28: 64 points -> 128 tangent rows (0..63 x-tangent, 64..127 y-tangent).
// Block: 256 thr = 4 waves; wave wn owns 128 rows x 64 cols (wn*64..).
// acc[8][4] (128 VGPR); B via depth-1 ping-pong bb[2][4] from
// FRAGMENT-MAJOR Wt2 (1KB coalesced per fragment; issued before the 64-MFMA
// slice that hides them). LDS = Apan(67.6KB) + smask(10KB) = 76KB ->
// 2 blocks/CU. Same MFMA fragments/order as v26 -> bit-identical.
// mfma_f32_16x16x32_f16: A[m=lane&15][k=quad*8+j], B[k=quad*8+j][n=lane&15],
//                        D[row=quad*4+reg][col=lane&15]  (verified layouts)
__global__ void __launch_bounds__(256, 2) tangent_fused_kernel(
    const float* __restrict__ Win,
    const _Float16* __restrict__ Wt2,         // fragment-major (see prep)
    const unsigned int* __restrict__ maskDw,  // [5][NPTS][8] dwords
    const float* __restrict__ Wout, float* __restrict__ out) {
  constexpr int SA = 264;   // A row stride (halves): 256 + 8 pad
  __shared__ alignas(16) _Float16 Apan[128 * SA];       // 67584 B
  __shared__ unsigned int smask[5 * 512];               // 10240 B

  const int tid = threadIdx.x;
  const int lane = tid & 63;
  const int wn = tid >> 6;          // wave = 64-col group
  const int l15 = lane & 15, quad = lane >> 4;
  const int p0 = blockIdx.x * 64;   // 64 points per block

  // ---- stage all 5 mask layers (64 pts x 8 dw each = 512 dw/layer)
#pragma unroll
  for (int i = 0; i < 10; ++i) {
    int idx = i * 256 + tid;        // 0..2559
    int layer = idx >> 9, rem = idx & 511;
    smask[idx] = maskDw[(size_t)layer * NPTS * 8 + (size_t)p0 * 8 + rem];
  }
  __syncthreads();

  // ---- init T1 into Apan: row<64 -> x-tangent (Win row 0), row>=64 -> y (row 1)
#pragma unroll
  for (int i = 0; i < 16; ++i) {
    int g = tid + 256 * i;          // 0..4095 col-groups of 8
    int row = g >> 5, cg = g & 31;
    int c0 = cg * 8, pt = row & 63, tg = row >> 6;
    unsigned dw = smask[pt * 8 + (c0 >> 5)];
    half8_t v;
#pragma unroll
    for (int e = 0; e < 8; ++e) {
      bool m = (dw >> ((cg & 3) * 8 + e)) & 1;
      v[e] = m ? (_Float16)Win[tg * 256 + c0 + e] : (_Float16)0.f;
    }
    *(half8_t*)&Apan[row * SA + c0] = v;
  }
  __syncthreads();                  // Apan init visible to all waves

  // ---- 4 layers: acc = A @ W_l (computed transposed), gate, back into Apan
  for (int l = 0; l < 4; ++l) {
    // fragment-major base for this (l, wn); fragment (s,nj) at +(s*4+nj)*512
    const _Float16* Bw = Wt2 + (size_t)(l * 4 + wn) * 32 * 512 + (size_t)lane * 8;

    floatx4 acc[8][4] = {};   // [mi][nj], element = D[n-local][m-local]
    half8_t bb[2][4];         // ping-pong B slices (static idx via full unroll)
#pragma unroll
    for (int nj = 0; nj < 4; ++nj)
      bb[0][nj] = *(const half8_t*)(Bw + (size_t)(0 * 4 + nj) * 512);

#pragma unroll
    for (int s = 0; s < 8; ++s) {
      // prefetch next B slice BEFORE this slice's MFMA block (~310 cyc cover)
      if (s < 7) {
#pragma unroll
        for (int nj = 0; nj < 4; ++nj)
          bb[(s + 1) & 1][nj] =
              *(const half8_t*)(Bw + (size_t)((s + 1) * 4 + nj) * 512);
      }
      half8_t af[8];
#pragma unroll
      for (int mi = 0; mi < 8; ++mi)
        af[mi] = *(const half8_t*)&Apan[(mi * 16 + l15) * SA + s * 32 + quad * 8];
      // SWAPPED operands: same products/order as v26 (bit-identical values),
      // transposed D layout (lane = one T-row m, 4 consecutive n per reg)
#pragma unroll
      for (int mi = 0; mi < 8; ++mi)
#pragma unroll
        for (int nj = 0; nj < 4; ++nj)
          acc[mi][nj] = __builtin_amdgcn_mfma_f32_16x16x32_f16(bb[s & 1][nj], af[mi], acc[mi][nj], 0, 0, 0);
    }
    __syncthreads();          // all Apan reads of this layer done
    // gated write-back: lane (l15,quad) of tile (mi,nj) holds rows m=mi*16+l15
    // (pt = m&63), cols C = wn*64 + nj*16 + quad*4 + r -> one b64 per (mi,nj)
    const unsigned int* ml = &smask[(l + 1) * 512];
    uint2 mPT[4];
#pragma unroll
    for (int q = 0; q < 4; ++q)
      mPT[q] = *(const uint2*)&ml[(q * 16 + l15) * 8 + wn * 2];
#pragma unroll
    for (int mi = 0; mi < 8; ++mi) {
      uint2 md = mPT[mi & 3];       // pt = (mi&3)*16 + l15
      int m = mi * 16 + l15;
#pragma unroll
      for (int nj = 0; nj < 4; ++nj) {
        unsigned dw = (nj < 2) ? md.x : md.y;
        int bitbase = (nj & 1) * 16 + quad * 4;
        half4_t v;
#pragma unroll
        for (int r = 0; r < 4; ++r)
          v[r] = ((dw >> (bitbase + r)) & 1) ? (_Float16)acc[mi][nj][r]
                                             : (_Float16)0.f;
        *(half4_t*)&Apan[m * SA + wn * 64 + nj * 16 + quad * 4] = v;
      }
    }
    __syncthreads();
  }

  // ---- finalize: T5 @ Wout via two MFMA chains per wave (rows wn*32..+32)
  {
    floatx4 f0 = {0.f, 0.f, 0.f, 0.f};
    floatx4 f1 = {0.f, 0.f, 0.f, 0.f};
#pragma unroll
    for (int kc = 0; kc < 8; ++kc) {
      half8_t a0 = *(const half8_t*)&Apan[(wn * 32 + l15) * SA + kc * 32 + quad * 8];
      half8_t a1 = *(const half8_t*)&Apan[(wn * 32 + 16 + l15) * SA + kc * 32 + quad * 8];
      half8_t b;
#pragma unroll
      for (int j = 0; j < 8; ++j) {
        int k = kc * 32 + quad * 8 + j;
        b[j] = (l15 < 2) ? (_Float16)Wout[2 * k + l15] : (_Float16)0.f;
      }
      f0 = __builtin_amdgcn_mfma_f32_16x16x32_f16(a0, b, f0, 0, 0, 0);
      f1 = __builtin_amdgcn_mfma_f32_16x16x32_f16(a1, b, f1, 0, 0, 0);
    }
    // D[row=quad*4+r][col=l15]: global row = wn*32 + c*16 + quad*4 + r;
    // row<64 -> x-tangent (v=-psi_x, f=p_x); row>=64 -> y (u=psi_y, g=p_y)
    if (l15 < 2) {
#pragma unroll
      for (int c = 0; c < 2; ++c) {
        floatx4 fc = c ? f1 : f0;
#pragma unroll
        for (int r = 0; r < 4; ++r) {
          int row = wn * 32 + c * 16 + quad * 4 + r;
          int pt = p0 + (row & 63);
          float val = fc[r];
          if (l15 == 0) {
            if (row < 64) out[NPTS + pt] = -val;      // v = -psi_x
            else          out[pt] = val;              // u =  psi_y
          } else {
            if (row < 64) out[3 * NPTS + pt] = val;   // f = p_x
            else          out[4 * NPTS + pt] = val;   // g = p_y
          }
        }
      }
    }
  }
}

// ---------------------------------------------------------------- launch
extern "C" void kernel_launch(void* const* d_in, const int* in_sizes, int n_in,
                              void* d_out, int out_size, void* d_ws, size_t ws_size,
                              hipStream_t stream) {
  const float* x = (const float*)d_in[0];
  const float* y = (const float*)d_in[1];
  const float* t = (const float*)d_in[2];
  const float* Win = (const float*)d_in[3];
  const float* b_in = (const float*)d_in[4];
  const float* Wh = (const float*)d_in[5];
  const float* b_h = (const float*)d_in[6];
  const float* Wout = (const float*)d_in[7];
  const float* b_out = (const float*)d_in[8];
  float* out = (float*)d_out;

  char* ws = (char*)d_ws;
  constexpr size_t MASK_SZ = (size_t)NPTS * 32;       // 2 MB per layer
  unsigned char* masks = (unsigned char*)ws;
  _Float16* Wt2 = (_Float16*)(ws + 5 * MASK_SZ);

  // weight transpose/cast/swizzle first (independent of fwd)
  prep_weights_kernel<<<1024, 256, 0, stream>>>(Wh, Wt2);

  // fp32 np-exact forward: masks L0..L4 + p  (128 pts/block — v20 final)
  fwd_fused_kernel<<<NPTS / 128, 1024, 0, stream>>>(
      x, y, t, Win, b_in, Wh, b_h, Wout, b_out, masks, out);

  // fused tangent chain: init + 4 MFMA layers + finalize (u,v,f,g)
  tangent_fused_kernel<<<NPTS / 64, 256, 0, stream>>>(
      Win, Wt2, (const unsigned int*)masks, Wout, out);
}

// Round 11
// 518.176 us; speedup vs baseline: 1.1484x; 1.0053x over previous
//
#include <hip/hip_runtime.h>
#include <hip/hip_bf16.h>

// N=65536 points, H=256, 4 hidden layers, ReLU MLP -> (psi,p).
// ReLU => piecewise linear => Hessians vanish; f = p_x, g = p_y (RHO=1).
// Pipeline:
//   1) fp32 forward (v20/v11 verbatim, ~400us) - FINAL. Eight experiments
//      bracket the s_load path's ~68% duty as the structural optimum.
//      Bit-exact np/BLAS chains throughout.
//   2) tangent kernel v29 = v26 geometry (32 pts/block) + OCCUPANCY:
//      breg[8][4] (128 VGPR whole-layer B) -> bb[2][4] depth-1 ping-pong
//      (32 VGPR, static idx via fully-unrolled s loop). VGPR ~115 fits
//      launch_bounds(256,4)'s 128 cap -> 4 blocks/CU (LDS 38.9KB x4 =
//      155.6KB), 16 waves/CU. v26's pipes (MFMA 33us, L2-B 30us, LDS 25us)
//      were serialized at 8 waves/CU; doubling TLP + 4 independent barrier
//      domains overlaps them. v28 (64pt) showed traffic isn't the lever
//      (occupancy unchanged -> +7us). Same fragments, same s-ascending
//      accumulation chains -> BIT-IDENTICAL output (absmax 6.103516e-05).
//      Pre-committed failure read: total~512 or FETCH explosion -> revert
//      v26, declare roofline.
// Workspace: masks 5x2MB | Wt2 512KB

#define NPTS 65536
#define HDIM 256

typedef _Float16 half8_t __attribute__((ext_vector_type(8)));
typedef _Float16 half4_t __attribute__((ext_vector_type(4)));
typedef float floatx4 __attribute__((ext_vector_type(4)));

// ---------------------------------------------------------------- fused fp32 forward (np/BLAS-exact) — v11/v20 verbatim
__global__ void __launch_bounds__(1024) fwd_fused_kernel(
    const float* __restrict__ x, const float* __restrict__ y, const float* __restrict__ t,
    const float* __restrict__ Win, const float* __restrict__ b_in,
    const float* __restrict__ Wh, const float* __restrict__ b_h,
    const float* __restrict__ Wout, const float* __restrict__ b_out,
    unsigned char* __restrict__ masks, float* __restrict__ out) {
  constexpr int SH = 257;              // odd stride: conflict-free b32
  __shared__ float hT[128 * SH];       // [pt][k]  131584 B
  __shared__ float pscr[16][132];      // wave partials for p (8448 B)

  const int tid = threadIdx.x;
  const int lane = tid & 63;
  const int w = __builtin_amdgcn_readfirstlane(tid >> 6);       // wave id 0..15
  const int c0 = w * 16;                                        // 16-col group
  const int p0 = blockIdx.x * 128;
  const int pA = p0 + lane;            // point A
  const int pB = p0 + 64 + lane;       // point B

  // ---- layer 1: dot = z @ Win (k ascending: x,y,t), then + b_in  [bit-exact]
  {
    float xa = x[pA], ya = y[pA], ta = t[pA];
    float xb = x[pB], yb = y[pB], tb = t[pB];
    unsigned ma = 0, mb = 0;
#pragma unroll
    for (int e = 0; e < 16; ++e) {
      int c = c0 + e;                  // uniform -> Win reads are scalar
      float w0 = Win[c], w1 = Win[256 + c], w2 = Win[512 + c], bb = b_in[c];
      float da = fmaf(xa, w0, 0.f);
      da = fmaf(ya, w1, da);
      da = fmaf(ta, w2, da);
      float aa = da + bb;
      bool posa = aa > 0.f;
      hT[lane * SH + c] = posa ? aa : 0.f;
      ma |= (posa ? 1u : 0u) << e;
      float db = fmaf(xb, w0, 0.f);
      db = fmaf(yb, w1, db);
      db = fmaf(tb, w2, db);
      float ab = db + bb;
      bool posb = ab > 0.f;
      hT[(64 + lane) * SH + c] = posb ? ab : 0.f;
      mb |= (posb ? 1u : 0u) << e;
    }
    *(unsigned short*)(masks + (size_t)pA * 32 + w * 2) = (unsigned short)ma;
    *(unsigned short*)(masks + (size_t)pB * 32 + w * 2) = (unsigned short)mb;
  }
  __syncthreads();

  // ---- hidden layers: single fp32 accumulator per element, k ascending, fmaf
  for (int l = 0; l < 4; ++l) {
    const float* Wl = Wh + (size_t)l * 65536 + c0;   // + uniform col offset
    float accA[16] = {};
    float accB[16] = {};
#pragma unroll 2
    for (int k = 0; k < 256; ++k) {
      float hA = hT[lane * SH + k];          // per-lane LDS, conflict-free
      float hB = hT[(64 + lane) * SH + k];
      const float* wr = Wl + k * 256;        // wave-uniform -> s_load_dwordx16
#pragma unroll
      for (int e = 0; e < 16; ++e) {
        float wv = wr[e];
        accA[e] = fmaf(hA, wv, accA[e]);
        accB[e] = fmaf(hB, wv, accB[e]);
      }
    }
    __syncthreads();                   // all hT reads done before overwrite
    unsigned ma = 0, mb = 0;
    float hnA[16], hnB[16];
#pragma unroll
    for (int e = 0; e < 16; ++e) {
      float bb = b_h[l * 256 + c0 + e];
      float aa = accA[e] + bb;
      bool posa = aa > 0.f;
      hnA[e] = posa ? aa : 0.f;
      ma |= (posa ? 1u : 0u) << e;
      float ab = accB[e] + bb;
      bool posb = ab > 0.f;
      hnB[e] = posb ? ab : 0.f;
      mb |= (posb ? 1u : 0u) << e;
    }
    *(unsigned short*)(masks + ((size_t)(l + 1) * NPTS + pA) * 32 + w * 2) =
        (unsigned short)ma;
    *(unsigned short*)(masks + ((size_t)(l + 1) * NPTS + pB) * 32 + w * 2) =
        (unsigned short)mb;
#pragma unroll
    for (int e = 0; e < 16; ++e) {
      hT[lane * SH + c0 + e] = hnA[e];
      hT[(64 + lane) * SH + c0 + e] = hnB[e];
    }
    __syncthreads();
  }

  // ---- p = h5 . Wout[:,1] + b_out[1]
  {
    float sA = 0.f, sB = 0.f;
#pragma unroll
    for (int e = 0; e < 16; ++e) {
      float wv = Wout[2 * (c0 + e) + 1];
      sA = fmaf(hT[lane * SH + c0 + e], wv, sA);
      sB = fmaf(hT[(64 + lane) * SH + c0 + e], wv, sB);
    }
    pscr[w][lane] = sA;
    pscr[w][64 + lane] = sB;
  }
  __syncthreads();
  if (tid < 128) {
    float s2 = 0.f;
#pragma unroll
    for (int g = 0; g < 16; ++g) s2 += pscr[g][tid];
    out[2 * NPTS + p0 + tid] = s2 + b_out[1];
  }
}

// ---------------------------------------------------------------- prep: Wh fp32 [l][k][n] -> fragment-major f16
// Wt2 flat index i = ((((l*4 + wn)*8 + s)*4 + nj)*64 + lane)*8 + j
// holds (f16)Wh[l][k][n] with k = s*32 + (lane>>4)*8 + j,
//                           n = wn*64 + nj*16 + (lane&15).
// A wave's B-fragment load (fixed l,wn,s,nj; lane 0..63; j 0..7) is then
// 64 x 16B = 1KB contiguous -> one fully-coalesced global_load_dwordx4.
__global__ void __launch_bounds__(256) prep_weights_kernel(
    const float* __restrict__ Wh, _Float16* __restrict__ Wt2) {
  int i = blockIdx.x * 256 + threadIdx.x;   // 0..262143
  int j = i & 7;
  int lane = (i >> 3) & 63;
  int nj = (i >> 9) & 3;
  int s = (i >> 11) & 7;
  int wn = (i >> 14) & 3;
  int l = i >> 16;
  int k = s * 32 + ((lane >> 4) << 3) + j;
  int n = wn * 64 + nj * 16 + (lane & 15);
  Wt2[i] = (_Float16)Wh[(size_t)l * 65536 + (size_t)k * 256 + n];
}

// ---------------------------------------------------------------- fused tangent chain (init + 4 layers + finalize)
// Block: 256 thr = 4 waves. 32 points -> 64 rows (0..31 x-tangent, 32..63 y).
// Tile M=64 x N=256; wave wn owns 64 rows x 64 cols. T lives in Apan (f16).
// v29: B via depth-1 ping-pong bb[2][4] (static idx, fully-unrolled s) from
// FRAGMENT-MAJOR Wt2 (1KB coalesced per fragment). VGPR ~115 -> 128 cap at
// launch_bounds(256,4) -> 4 blocks/CU (LDS 155.6KB), 16 waves/CU for
// cross-block overlap of MFMA / B-loads / LDS.
// mfma(bf, af, acc) OPERAND SWAP -> D[row = n-local quad*4+reg]
// [col = m-local l15]: lane holds 4 consecutive n for one row m ->
// write-back is 16 ds_write_b64. Finalize = one MFMA chain per wave.
// mfma_f32_16x16x32_f16: A[m=lane&15][k=quad*8+j], B[k=quad*8+j][n=lane&15],
//                        D[row=quad*4+reg][col=lane&15]  (verified layouts)
__global__ void __launch_bounds__(256, 4) tangent_fused_kernel(
    const float* __restrict__ Win,
    const _Float16* __restrict__ Wt2,         // fragment-major (see prep)
    const unsigned int* __restrict__ maskDw,  // [5][NPTS][8] dwords
    const float* __restrict__ Wout, float* __restrict__ out) {
  constexpr int SA = 264;   // A row stride (halves): 256 + 8 pad
  __shared__ alignas(16) _Float16 Apan[64 * SA];        // 33792 B
  __shared__ unsigned int smask[5 * 256];               // 5120 B

  const int tid = threadIdx.x;
  const int lane = tid & 63;
  const int wn = tid >> 6;          // wave = 64-col group
  const int l15 = lane & 15, quad = lane >> 4;
  const int p0 = blockIdx.x * 32;   // 32 points per block

  // ---- stage all 5 mask layers (32 pts x 8 dw each)
#pragma unroll
  for (int i = 0; i < 5; ++i)
    smask[i * 256 + tid] = maskDw[(size_t)i * NPTS * 8 + (size_t)p0 * 8 + tid];
  __syncthreads();

  // ---- init T1 into Apan: row<32 -> x-tangent (Win row 0), row>=32 -> y (row 1)
#pragma unroll
  for (int i = 0; i < 8; ++i) {
    int g = tid + 256 * i;          // 0..2047 col-groups of 8
    int row = g >> 5, cg = g & 31;
    int c0 = cg * 8, pt = row & 31, tg = row >> 5;
    unsigned dw = smask[pt * 8 + (c0 >> 5)];
    half8_t v;
#pragma unroll
    for (int e = 0; e < 8; ++e) {
      bool m = (dw >> ((cg & 3) * 8 + e)) & 1;
      v[e] = m ? (_Float16)Win[tg * 256 + c0 + e] : (_Float16)0.f;
    }
    *(half8_t*)&Apan[row * SA + c0] = v;
  }
  __syncthreads();                  // Apan init visible to all waves

  // ---- 4 layers: acc = A @ W_l (computed transposed), gate, back into Apan
  for (int l = 0; l < 4; ++l) {
    // fragment-major base for this (l, wn): fragments are 1KB apart,
    // this wave's lane slice is lane*16B within each.
    const _Float16* Bw = Wt2 + (size_t)(l * 4 + wn) * 32 * 512 + (size_t)lane * 8;

    floatx4 acc[4][4] = {};   // [mi][nj], element = D[n-local][m-local]
    half8_t bb[2][4];         // ping-pong B slices (s fully unrolled -> static)
#pragma unroll
    for (int nj = 0; nj < 4; ++nj)
      bb[0][nj] = *(const half8_t*)(Bw + (size_t)nj * 512);

#pragma unroll
    for (int s = 0; s < 8; ++s) {     // s = kp*2+ks of v19: same k order
      // prefetch next slice before this slice's MFMAs (TLP covers the rest)
      if (s < 7) {
#pragma unroll
        for (int nj = 0; nj < 4; ++nj)
          bb[(s + 1) & 1][nj] =
              *(const half8_t*)(Bw + (size_t)((s + 1) * 4 + nj) * 512);
      }
#pragma unroll
      for (int mi = 0; mi < 4; ++mi) {
        half8_t af = *(const half8_t*)&Apan[(mi * 16 + l15) * SA + s * 32 + quad * 8];
        // SWAPPED operands: same products/order as v26 (bit-identical),
        // transposed D layout (lane = one T-row m, 4 consecutive n per reg)
#pragma unroll
        for (int nj = 0; nj < 4; ++nj)
          acc[mi][nj] = __builtin_amdgcn_mfma_f32_16x16x32_f16(bb[s & 1][nj], af, acc[mi][nj], 0, 0, 0);
      }
    }
    __syncthreads();          // all Apan reads of this layer done
    // gated write-back: lane (l15,quad) of tile (mi,nj) holds rows m=mi*16+l15,
    // cols C = wn*64 + nj*16 + quad*4 + r  -> one b64 per (mi,nj)
    const unsigned int* ml = &smask[(l + 1) * 256];
    uint2 mA = *(const uint2*)&ml[l15 * 8 + wn * 2];         // pt = l15
    uint2 mB = *(const uint2*)&ml[(16 + l15) * 8 + wn * 2];  // pt = 16+l15
#pragma unroll
    for (int mi = 0; mi < 4; ++mi) {
      uint2 md = (mi & 1) ? mB : mA;
      int m = mi * 16 + l15;
#pragma unroll
      for (int nj = 0; nj < 4; ++nj) {
        unsigned dw = (nj < 2) ? md.x : md.y;
        int bitbase = (nj & 1) * 16 + quad * 4;
        half4_t v;
#pragma unroll
        for (int r = 0; r < 4; ++r)
          v[r] = ((dw >> (bitbase + r)) & 1) ? (_Float16)acc[mi][nj][r]
                                             : (_Float16)0.f;
        *(half4_t*)&Apan[m * SA + wn * 64 + nj * 16 + quad * 4] = v;
      }
    }
    __syncthreads();
  }

  // ---- finalize: T5 @ Wout via one MFMA chain per wave (rows wn*16..+15)
  {
    floatx4 facc = {0.f, 0.f, 0.f, 0.f};
#pragma unroll
    for (int kc = 0; kc < 8; ++kc) {
      half8_t a = *(const half8_t*)&Apan[(wn * 16 + l15) * SA + kc * 32 + quad * 8];
      half8_t b;
#pragma unroll
      for (int j = 0; j < 8; ++j) {
        int k = kc * 32 + quad * 8 + j;
        b[j] = (l15 < 2) ? (_Float16)Wout[2 * k + l15] : (_Float16)0.f;
      }
      facc = __builtin_amdgcn_mfma_f32_16x16x32_f16(a, b, facc, 0, 0, 0);
    }
    // D[row=quad*4+r][col=l15]: global row = wn*16 + quad*4 + r; col 0 -> psi
    // derivative dot (u/v), col 1 -> p derivative dot (f/g)
    if (l15 < 2) {
#pragma unroll
      for (int r = 0; r < 4; ++r) {
        int row = wn * 16 + quad * 4 + r;
        int pt = p0 + (row & 31);
        float val = facc[r];
        if (l15 == 0) {
          if (row < 32) out[NPTS + pt] = -val;      // v = -psi_x
          else          out[pt] = val;              // u =  psi_y
        } else {
          if (row < 32) out[3 * NPTS + pt] = val;   // f = p_x
          else          out[4 * NPTS + pt] = val;   // g = p_y
        }
      }
    }
  }
}

// ---------------------------------------------------------------- launch
extern "C" void kernel_launch(void* const* d_in, const int* in_sizes, int n_in,
                              void* d_out, int out_size, void* d_ws, size_t ws_size,
                              hipStream_t stream) {
  const float* x = (const float*)d_in[0];
  const float* y = (const float*)d_in[1];
  const float* t = (const float*)d_in[2];
  const float* Win = (const float*)d_in[3];
  const float* b_in = (const float*)d_in[4];
  const float* Wh = (const float*)d_in[5];
  const float* b_h = (const float*)d_in[6];
  const float* Wout = (const float*)d_in[7];
  const float* b_out = (const float*)d_in[8];
  float* out = (float*)d_out;

  char* ws = (char*)d_ws;
  constexpr size_t MASK_SZ = (size_t)NPTS * 32;       // 2 MB per layer
  unsigned char* masks = (unsigned char*)ws;
  _Float16* Wt2 = (_Float16*)(ws + 5 * MASK_SZ);

  // weight transpose/cast/swizzle first (independent of fwd)
  prep_weights_kernel<<<1024, 256, 0, stream>>>(Wh, Wt2);

  // fp32 np-exact forward: masks L0..L4 + p  (128 pts/block — v20 final)
  fwd_fused_kernel<<<NPTS / 128, 1024, 0, stream>>>(
      x, y, t, Win, b_in, Wh, b_h, Wout, b_out, masks, out);

  // fused tangent chain: init + 4 MFMA layers + finalize (u,v,f,g)
  tangent_fused_kernel<<<NPTS / 32, 256, 0, stream>>>(
      Win, Wt2, (const unsigned int*)masks, Wout, out);
}

// Round 12
// 509.232 us; speedup vs baseline: 1.1686x; 1.0176x over previous
//
#include <hip/hip_runtime.h>
#include <hip/hip_bf16.h>

// N=65536 points, H=256, 4 hidden layers, ReLU MLP -> (psi,p).
// ReLU => piecewise linear => Hessians vanish; f = p_x, g = p_y (RHO=1).
// FINAL (v26, measured 512.5us):
//   1) fp32 forward (v20/v11 verbatim, ~400us): bit-exact np/BLAS chains
//      (mask integrity demands it: a ReLU-boundary flip injects O(0.01)
//      tangent error vs ~4e-4 threshold). Nine experiments bracket the
//      scalar-supply 68%-VALU-duty point as structural optimum; ~85% of
//      the issue-port-corrected achievable ceiling (m07: 103TF scalar FMA).
//   2) tangent kernel (v26): whole-layer B in registers from FRAGMENT-MAJOR
//      Wt2 (B-fragment load = 64 lanes x 16B = 1KB contiguous, coalesced);
//      no Bpan round-trip. ~106us vs 33us max-pipe floor; traffic (v28)
//      and occupancy (v29) levers both measured null -> overlapped-pipe
//      optimum for this decomposition.
// Workspace: masks 5x2MB | Wt2 512KB

#define NPTS 65536
#define HDIM 256

typedef _Float16 half8_t __attribute__((ext_vector_type(8)));
typedef _Float16 half4_t __attribute__((ext_vector_type(4)));
typedef float floatx4 __attribute__((ext_vector_type(4)));

// ---------------------------------------------------------------- fused fp32 forward (np/BLAS-exact) — v11/v20 verbatim
__global__ void __launch_bounds__(1024) fwd_fused_kernel(
    const float* __restrict__ x, const float* __restrict__ y, const float* __restrict__ t,
    const float* __restrict__ Win, const float* __restrict__ b_in,
    const float* __restrict__ Wh, const float* __restrict__ b_h,
    const float* __restrict__ Wout, const float* __restrict__ b_out,
    unsigned char* __restrict__ masks, float* __restrict__ out) {
  constexpr int SH = 257;              // odd stride: conflict-free b32
  __shared__ float hT[128 * SH];       // [pt][k]  131584 B
  __shared__ float pscr[16][132];      // wave partials for p (8448 B)

  const int tid = threadIdx.x;
  const int lane = tid & 63;
  const int w = __builtin_amdgcn_readfirstlane(tid >> 6);       // wave id 0..15
  const int c0 = w * 16;                                        // 16-col group
  const int p0 = blockIdx.x * 128;
  const int pA = p0 + lane;            // point A
  const int pB = p0 + 64 + lane;       // point B

  // ---- layer 1: dot = z @ Win (k ascending: x,y,t), then + b_in  [bit-exact]
  {
    float xa = x[pA], ya = y[pA], ta = t[pA];
    float xb = x[pB], yb = y[pB], tb = t[pB];
    unsigned ma = 0, mb = 0;
#pragma unroll
    for (int e = 0; e < 16; ++e) {
      int c = c0 + e;                  // uniform -> Win reads are scalar
      float w0 = Win[c], w1 = Win[256 + c], w2 = Win[512 + c], bb = b_in[c];
      float da = fmaf(xa, w0, 0.f);
      da = fmaf(ya, w1, da);
      da = fmaf(ta, w2, da);
      float aa = da + bb;
      bool posa = aa > 0.f;
      hT[lane * SH + c] = posa ? aa : 0.f;
      ma |= (posa ? 1u : 0u) << e;
      float db = fmaf(xb, w0, 0.f);
      db = fmaf(yb, w1, db);
      db = fmaf(tb, w2, db);
      float ab = db + bb;
      bool posb = ab > 0.f;
      hT[(64 + lane) * SH + c] = posb ? ab : 0.f;
      mb |= (posb ? 1u : 0u) << e;
    }
    *(unsigned short*)(masks + (size_t)pA * 32 + w * 2) = (unsigned short)ma;
    *(unsigned short*)(masks + (size_t)pB * 32 + w * 2) = (unsigned short)mb;
  }
  __syncthreads();

  // ---- hidden layers: single fp32 accumulator per element, k ascending, fmaf
  for (int l = 0; l < 4; ++l) {
    const float* Wl = Wh + (size_t)l * 65536 + c0;   // + uniform col offset
    float accA[16] = {};
    float accB[16] = {};
#pragma unroll 2
    for (int k = 0; k < 256; ++k) {
      float hA = hT[lane * SH + k];          // per-lane LDS, conflict-free
      float hB = hT[(64 + lane) * SH + k];
      const float* wr = Wl + k * 256;        // wave-uniform -> s_load_dwordx16
#pragma unroll
      for (int e = 0; e < 16; ++e) {
        float wv = wr[e];
        accA[e] = fmaf(hA, wv, accA[e]);
        accB[e] = fmaf(hB, wv, accB[e]);
      }
    }
    __syncthreads();                   // all hT reads done before overwrite
    unsigned ma = 0, mb = 0;
    float hnA[16], hnB[16];
#pragma unroll
    for (int e = 0; e < 16; ++e) {
      float bb = b_h[l * 256 + c0 + e];
      float aa = accA[e] + bb;
      bool posa = aa > 0.f;
      hnA[e] = posa ? aa : 0.f;
      ma |= (posa ? 1u : 0u) << e;
      float ab = accB[e] + bb;
      bool posb = ab > 0.f;
      hnB[e] = posb ? ab : 0.f;
      mb |= (posb ? 1u : 0u) << e;
    }
    *(unsigned short*)(masks + ((size_t)(l + 1) * NPTS + pA) * 32 + w * 2) =
        (unsigned short)ma;
    *(unsigned short*)(masks + ((size_t)(l + 1) * NPTS + pB) * 32 + w * 2) =
        (unsigned short)mb;
#pragma unroll
    for (int e = 0; e < 16; ++e) {
      hT[lane * SH + c0 + e] = hnA[e];
      hT[(64 + lane) * SH + c0 + e] = hnB[e];
    }
    __syncthreads();
  }

  // ---- p = h5 . Wout[:,1] + b_out[1]
  {
    float sA = 0.f, sB = 0.f;
#pragma unroll
    for (int e = 0; e < 16; ++e) {
      float wv = Wout[2 * (c0 + e) + 1];
      sA = fmaf(hT[lane * SH + c0 + e], wv, sA);
      sB = fmaf(hT[(64 + lane) * SH + c0 + e], wv, sB);
    }
    pscr[w][lane] = sA;
    pscr[w][64 + lane] = sB;
  }
  __syncthreads();
  if (tid < 128) {
    float s2 = 0.f;
#pragma unroll
    for (int g = 0; g < 16; ++g) s2 += pscr[g][tid];
    out[2 * NPTS + p0 + tid] = s2 + b_out[1];
  }
}

// ---------------------------------------------------------------- prep: Wh fp32 [l][k][n] -> fragment-major f16
// Wt2 flat index i = ((((l*4 + wn)*8 + s)*4 + nj)*64 + lane)*8 + j
// holds (f16)Wh[l][k][n] with k = s*32 + (lane>>4)*8 + j,
//                           n = wn*64 + nj*16 + (lane&15).
// A wave's B-fragment load (fixed l,wn,s,nj; lane 0..63; j 0..7) is then
// 64 x 16B = 1KB contiguous -> one fully-coalesced global_load_dwordx4.
__global__ void __launch_bounds__(256) prep_weights_kernel(
    const float* __restrict__ Wh, _Float16* __restrict__ Wt2) {
  int i = blockIdx.x * 256 + threadIdx.x;   // 0..262143
  int j = i & 7;
  int lane = (i >> 3) & 63;
  int nj = (i >> 9) & 3;
  int s = (i >> 11) & 7;
  int wn = (i >> 14) & 3;
  int l = i >> 16;
  int k = s * 32 + ((lane >> 4) << 3) + j;
  int n = wn * 64 + nj * 16 + (lane & 15);
  Wt2[i] = (_Float16)Wh[(size_t)l * 65536 + (size_t)k * 256 + n];
}

// ---------------------------------------------------------------- fused tangent chain (init + 4 layers + finalize)
// Block: 256 thr = 4 waves. 32 points -> 64 rows (0..31 x-tangent, 32..63 y).
// Tile M=64 x N=256; wave wn owns 64 rows x 64 cols. T lives in Apan (f16).
// v26: whole-layer B in registers (breg[8][4]), loaded from FRAGMENT-MAJOR
// Wt2 -> 32 fully-coalesced 1KB dwordx4 loads per wave per layer at layer
// top (compiler early-issues, counted vmcnt; latency hides under af+MFMA).
// No Bpan. LDS = Apan + smask = 38.9KB.
// mfma(bf, af, acc) OPERAND SWAP -> D[row = n-local quad*4+reg]
// [col = m-local l15]: lane holds 4 consecutive n for one row m ->
// write-back is 16 ds_write_b64. Finalize = one MFMA chain per wave.
// mfma_f32_16x16x32_f16: A[m=lane&15][k=quad*8+j], B[k=quad*8+j][n=lane&15],
//                        D[row=quad*4+reg][col=lane&15]  (verified layouts)
__global__ void __launch_bounds__(256, 2) tangent_fused_kernel(
    const float* __restrict__ Win,
    const _Float16* __restrict__ Wt2,         // fragment-major (see prep)
    const unsigned int* __restrict__ maskDw,  // [5][NPTS][8] dwords
    const float* __restrict__ Wout, float* __restrict__ out) {
  constexpr int SA = 264;   // A row stride (halves): 256 + 8 pad
  __shared__ alignas(16) _Float16 Apan[64 * SA];        // 33792 B
  __shared__ unsigned int smask[5 * 256];               // 5120 B

  const int tid = threadIdx.x;
  const int lane = tid & 63;
  const int wn = tid >> 6;          // wave = 64-col group
  const int l15 = lane & 15, quad = lane >> 4;
  const int p0 = blockIdx.x * 32;   // 32 points per block

  // ---- stage all 5 mask layers (32 pts x 8 dw each)
#pragma unroll
  for (int i = 0; i < 5; ++i)
    smask[i * 256 + tid] = maskDw[(size_t)i * NPTS * 8 + (size_t)p0 * 8 + tid];
  __syncthreads();

  // ---- init T1 into Apan: row<32 -> x-tangent (Win row 0), row>=32 -> y (row 1)
#pragma unroll
  for (int i = 0; i < 8; ++i) {
    int g = tid + 256 * i;          // 0..2047 col-groups of 8
    int row = g >> 5, cg = g & 31;
    int c0 = cg * 8, pt = row & 31, tg = row >> 5;
    unsigned dw = smask[pt * 8 + (c0 >> 5)];
    half8_t v;
#pragma unroll
    for (int e = 0; e < 8; ++e) {
      bool m = (dw >> ((cg & 3) * 8 + e)) & 1;
      v[e] = m ? (_Float16)Win[tg * 256 + c0 + e] : (_Float16)0.f;
    }
    *(half8_t*)&Apan[row * SA + c0] = v;
  }
  __syncthreads();                  // Apan init visible to all waves

  // ---- 4 layers: acc = A @ W_l (computed transposed), gate, back into Apan
  for (int l = 0; l < 4; ++l) {
    // fragment-major base for this (l, wn): fragments are 1KB apart,
    // this wave's lane slice is lane*16B within each.
    const _Float16* Bw = Wt2 + ((size_t)(l * 4 + wn) * 32 + 0) * 512 + (size_t)lane * 8;

    // ---- load ALL 32 B fragments for this layer: fully-coalesced 1KB each.
    half8_t breg[8][4];
#pragma unroll
    for (int s = 0; s < 8; ++s)
#pragma unroll
      for (int nj = 0; nj < 4; ++nj)
        breg[s][nj] = *(const half8_t*)(Bw + (size_t)(s * 4 + nj) * 512);

    floatx4 acc[4][4] = {};   // [mi][nj], element = D[n-local][m-local]
#pragma unroll
    for (int s = 0; s < 8; ++s) {     // s = kp*2+ks of v19: same k order
      half8_t af[4];
#pragma unroll
      for (int mi = 0; mi < 4; ++mi)
        af[mi] = *(const half8_t*)&Apan[(mi * 16 + l15) * SA + s * 32 + quad * 8];
      // SWAPPED operands: same products/order as v19 (bit-identical values),
      // transposed D layout (lane = one T-row m, 4 consecutive n per reg)
#pragma unroll
      for (int mi = 0; mi < 4; ++mi)
#pragma unroll
        for (int nj = 0; nj < 4; ++nj)
          acc[mi][nj] = __builtin_amdgcn_mfma_f32_16x16x32_f16(breg[s][nj], af[mi], acc[mi][nj], 0, 0, 0);
    }
    __syncthreads();          // all Apan reads of this layer done
    // gated write-back: lane (l15,quad) of tile (mi,nj) holds rows m=mi*16+l15,
    // cols C = wn*64 + nj*16 + quad*4 + r  -> one b64 per (mi,nj)
    const unsigned int* ml = &smask[(l + 1) * 256];
    uint2 mA = *(const uint2*)&ml[l15 * 8 + wn * 2];         // pt = l15
    uint2 mB = *(const uint2*)&ml[(16 + l15) * 8 + wn * 2];  // pt = 16+l15
#pragma unroll
    for (int mi = 0; mi < 4; ++mi) {
      uint2 md = (mi & 1) ? mB : mA;
      int m = mi * 16 + l15;
#pragma unroll
      for (int nj = 0; nj < 4; ++nj) {
        unsigned dw = (nj < 2) ? md.x : md.y;
        int bitbase = (nj & 1) * 16 + quad * 4;
        half4_t v;
#pragma unroll
        for (int r = 0; r < 4; ++r)
          v[r] = ((dw >> (bitbase + r)) & 1) ? (_Float16)acc[mi][nj][r]
                                             : (_Float16)0.f;
        *(half4_t*)&Apan[m * SA + wn * 64 + nj * 16 + quad * 4] = v;
      }
    }
    __syncthreads();
  }

  // ---- finalize: T5 @ Wout via one MFMA chain per wave (rows wn*16..+15)
  {
    floatx4 facc = {0.f, 0.f, 0.f, 0.f};
#pragma unroll
    for (int kc = 0; kc < 8; ++kc) {
      half8_t a = *(const half8_t*)&Apan[(wn * 16 + l15) * SA + kc * 32 + quad * 8];
      half8_t b;
#pragma unroll
      for (int j = 0; j < 8; ++j) {
        int k = kc * 32 + quad * 8 + j;
        b[j] = (l15 < 2) ? (_Float16)Wout[2 * k + l15] : (_Float16)0.f;
      }
      facc = __builtin_amdgcn_mfma_f32_16x16x32_f16(a, b, facc, 0, 0, 0);
    }
    // D[row=quad*4+r][col=l15]: global row = wn*16 + quad*4 + r; col 0 -> psi
    // derivative dot (u/v), col 1 -> p derivative dot (f/g)
    if (l15 < 2) {
#pragma unroll
      for (int r = 0; r < 4; ++r) {
        int row = wn * 16 + quad * 4 + r;
        int pt = p0 + (row & 31);
        float val = facc[r];
        if (l15 == 0) {
          if (row < 32) out[NPTS + pt] = -val;      // v = -psi_x
          else          out[pt] = val;              // u =  psi_y
        } else {
          if (row < 32) out[3 * NPTS + pt] = val;   // f = p_x
          else          out[4 * NPTS + pt] = val;   // g = p_y
        }
      }
    }
  }
}

// ---------------------------------------------------------------- launch
extern "C" void kernel_launch(void* const* d_in, const int* in_sizes, int n_in,
                              void* d_out, int out_size, void* d_ws, size_t ws_size,
                              hipStream_t stream) {
  const float* x = (const float*)d_in[0];
  const float* y = (const float*)d_in[1];
  const float* t = (const float*)d_in[2];
  const float* Win = (const float*)d_in[3];
  const float* b_in = (const float*)d_in[4];
  const float* Wh = (const float*)d_in[5];
  const float* b_h = (const float*)d_in[6];
  const float* Wout = (const float*)d_in[7];
  const float* b_out = (const float*)d_in[8];
  float* out = (float*)d_out;

  char* ws = (char*)d_ws;
  constexpr size_t MASK_SZ = (size_t)NPTS * 32;       // 2 MB per layer
  unsigned char* masks = (unsigned char*)ws;
  _Float16* Wt2 = (_Float16*)(ws + 5 * MASK_SZ);

  // weight transpose/cast/swizzle first (independent of fwd)
  prep_weights_kernel<<<1024, 256, 0, stream>>>(Wh, Wt2);

  // fp32 np-exact forward: masks L0..L4 + p
  fwd_fused_kernel<<<NPTS / 128, 1024, 0, stream>>>(
      x, y, t, Win, b_in, Wh, b_h, Wout, b_out, masks, out);

  // fused tangent chain: init + 4 MFMA layers + finalize (u,v,f,g)
  tangent_fused_kernel<<<NPTS / 32, 256, 0, stream>>>(
      Win, Wt2, (const unsigned int*)masks, Wout, out);
}